// Round 7
// baseline (321.579 us; speedup 1.0000x reference)
//
#include <hip/hip_runtime.h>

#define HHI 1024
#define WWI 1024
#define NI  16
#define HWSZ (HHI * WWI)
#define EPSF  1.1920929e-07f
#define EPS64 7.62939453125e-06f   // 64*EPSF (exact)
#define T1 0.3249196962329063f     // tan(pi/10)
#define T2 1.3763819204711735f     // tan(3pi/10)

#define SW 64                      // cols per wave (1 per lane)
#define RW 16                      // output rows per wave
#define GX  (WWI / SW)             // 16
#define GYB (HHI / (RW * 4))       // 16 (block = 4 waves stacked = 64 rows)
#define NB  (GX * GYB * NI)        // 4096 blocks
#define FR_IMG 8176                // frame pixels per image (2px border)
#define FR_TOT (FR_IMG * NI)       // 130816

__device__ __forceinline__ int clampi(int v, int hi) { return v < 0 ? 0 : (v > hi ? hi : v); }
__device__ __forceinline__ int refli(int v, int n)  { return v < 0 ? -v : (v >= n ? 2*n-2-v : v); }
__device__ __forceinline__ float frcp(float x) { return __builtin_amdgcn_rcpf(x); }
__device__ __forceinline__ float shf(float v, int abyte) {
    return __int_as_float(__builtin_amdgcn_ds_bpermute(abyte, __float_as_int(v)));
}

// One pipeline stage. POS literal 0..4 (H rings mod-5, zero-cost under unroll).
// E rows are 3-deep shift registers (renamed away inside unrolled groups).
#define STAGE(POS, IDX, DOPRED, DOOUT) do {                                           \
    const int i_ = (IDX);                                                             \
    {                                                                                 \
        const int gy_ = clampi(Y0 - 2 + i_, HHI - 1);                                 \
        const float* trow_ = timg + (size_t)gy_ * WWI;                                \
        const float c_ = trow_[x];                                                    \
        float m1 = shf(c_, am1), m2 = shf(c_, am2);                                   \
        float p1 = shf(c_, ap1), p2 = shf(c_, ap2);                                   \
        if (lane < 2)  { m2 = trow_[cxm2]; if (lane == 0)  m1 = trow_[cxm1]; }        \
        if (lane > 61) { p2 = trow_[cxp2]; if (lane == 63) p1 = trow_[cxp1]; }        \
        const float s04 = m2 + p2, s13 = m1 + p1;                                     \
        H1[POS] = s04 - 2.f * c_;                     /* [1,0,-2,0,1]  */             \
        H2[POS] = s04 + 4.f * s13 + 6.f * c_;         /* [1,4,6,4,1]   */             \
        H3[POS] = (p2 - m2) + 2.f * (p1 - m1);        /* [-1,-2,0,2,1] */             \
    }                                                                                 \
    if (DOPRED) {                                                                     \
        ET = EM; EM = EB; ETL = EML; EML = EBL; ETR = EMR; EMR = EBR;                 \
        const int gp_ = refli(Y0 + i_ - 3, HHI);                                      \
        const float* prow_ = pimg + (size_t)gp_ * WWI;                                \
        EB = __expf(prow_[x]);                                                        \
        if (lane == 0 || lane == 63) {                                                \
            const float pv_ = prow_[lane ? pcR : pcL];                                \
            const float ev_ = __expf(pv_);                                            \
            if (lane) EBR = ev_; else EBL = ev_;                                      \
        }                                                                             \
    }                                                                                 \
    if (DOOUT) {                                                                      \
        const int y_ = Y0 + i_ - 4;                                                   \
        const int q0=(POS+1)%5, q1=(POS+2)%5, q2=(POS+3)%5, q3=(POS+4)%5, q4=POS;     \
        float gxx = (H1[q0]+H1[q4]) + 4.f*(H1[q1]+H1[q3]) + 6.f*H1[q2];               \
        float gyy = (H2[q0]+H2[q4]) - 2.f*H2[q2];                                     \
        float gxy = (H3[q4]-H3[q0]) + 2.f*(H3[q3]-H3[q1]);                            \
        float sarg = EPS64 - gxy;                                                     \
        float num = (sarg > 0.f) ? gyy : ((sarg < 0.f) ? -gyy : 0.f);                 \
        float v = num * frcp(gxx + EPS64);                                            \
        bool c2v = (v > T2);                                                          \
        bool c1v = (v > T1) & !c2v;                                                   \
        bool c0v = (v >= -T1) & (v <= T1);                                            \
        bool c3v = (v < -T2);                                                         \
        bool have = c2v | c1v | c0v | c3v;       /* NaN -> none */                    \
        float elT = l0  ? ETL : shf(ET, am1);                                         \
        float erT = l63 ? ETR : shf(ET, ap1);                                         \
        float elM = l0  ? EML : shf(EM, am1);                                         \
        float erM = l63 ? EMR : shf(EM, ap1);                                         \
        float elB = l0  ? EBL : shf(EB, am1);                                         \
        float erB = l63 ? EBR : shf(EB, ap1);                                         \
        float d1 = c0v ? elM : (c2v ? ET : (c1v ? erT : elT));                        \
        float d2 = c0v ? erM : (c2v ? EB : (c1v ? elB : erB));                        \
        float ec = EM;                                                                \
        float val = ec * frcp(d1 + ec + d2 + EPSF);                                   \
        bool ok = have & mx & (y_ >= 2) & (y_ <= HHI - 3);                            \
        term += ok ? val : 0.f;                                                       \
    }                                                                                 \
} while (0)

template <bool USE_WS>
__global__ __launch_bounds__(256, 8) void nms_main(
    const float* __restrict__ tru, const float* __restrict__ prd,
    float* __restrict__ partial)
{
    __shared__ float sred[4];
    const int tid  = threadIdx.x;
    const int lane = tid & 63;
    const int wave = __builtin_amdgcn_readfirstlane(tid >> 6);
    const int z = blockIdx.z;
    const float* timg = tru + (size_t)z * HWSZ;
    const float* pimg = prd + (size_t)z * HWSZ;
    float term = 0.f;

    // -------- interior: per-wave 64x16 tile, 1 col/lane, shuffle halos --------
    const int X0 = blockIdx.x * SW;
    const int x  = X0 + lane;
    const int Y0 = blockIdx.y * (RW * 4) + wave * RW;
    const bool l0 = (lane == 0), l63 = (lane == 63);
    const bool mx = (x >= 2) & (x <= WWI - 3);
    // bpermute byte-addresses, reused for every shuffle
    const int am1 = ((lane - 1) & 63) << 2;
    const int am2 = ((lane - 2) & 63) << 2;
    const int ap1 = ((lane + 1) & 63) << 2;
    const int ap2 = ((lane + 2) & 63) << 2;
    // clamped halo columns (only read on edge lanes)
    const int cxm1 = clampi(x - 1, WWI - 1);
    const int cxm2 = clampi(x - 2, WWI - 1);
    const int cxp1 = clampi(x + 1, WWI - 1);
    const int cxp2 = clampi(x + 2, WWI - 1);
    // reflected pred halo columns (wave-uniform)
    const int pcL = refli(X0 - 1, WWI);
    const int pcR = refli(X0 + SW, WWI);

    float H1[5], H2[5], H3[5];
    float ET = 0.f, EM = 0.f, EB = 0.f;
    float ETL = 0.f, EML = 0.f, EBL = 0.f, ETR = 0.f, EMR = 0.f, EBR = 0.f;

    // stages i=0..19: true rows Y0-2..Y0+17; pred from i=2; outputs y=Y0..Y0+15
    STAGE(0, 0, 0, 0);
    STAGE(1, 1, 0, 0);
    STAGE(2, 2, 1, 0);
    STAGE(3, 3, 1, 0);
    STAGE(4, 4, 1, 1);
    #pragma unroll 1
    for (int g = 1; g < 4; ++g) {
        const int ib = g * 5;
        STAGE(0, ib + 0, 1, 1);
        STAGE(1, ib + 1, 1, 1);
        STAGE(2, ib + 2, 1, 1);
        STAGE(3, ib + 3, 1, 1);
        STAGE(4, ib + 4, 1, 1);
    }

    // -------- frame epilogue: 2-px border, exact nested replicate-pad cascade,
    // 8 pixels per wave on lanes 0..7 --------
    {
        const int wid = (((z * gridDim.y) + blockIdx.y) * gridDim.x + blockIdx.x) * 4 + wave;
        int fp = wid * 8 + lane;
        const bool valid = (lane < 8) && (fp < FR_TOT);
        if (fp >= FR_TOT) fp = FR_TOT - 1;
        const int fz = fp / FR_IMG;          // const divisor -> magic mul
        const int p  = fp - fz * FR_IMG;
        const float* ftim = tru + (size_t)fz * HWSZ;
        const float* fpim = prd + (size_t)fz * HWSZ;
        int y, xx;
        if (p < 2048)      { y = p >> 10;                   xx = p & 1023; }
        else if (p < 4096) { y = 1022 + ((p - 2048) >> 10); xx = p & 1023; }
        else { int q = p - 4096; y = 2 + (q >> 2); int xi = q & 3; xx = (xi < 2) ? xi : 1020 + xi; }

        int R1[3], C1[3], R2[3][3], C2[3][3];
        #pragma unroll
        for (int a = 0; a < 3; ++a) { R1[a] = clampi(y + a - 1, HHI - 1); C1[a] = clampi(xx + a - 1, WWI - 1); }
        #pragma unroll
        for (int a = 0; a < 3; ++a)
            #pragma unroll
            for (int e = 0; e < 3; ++e) {
                R2[a][e] = clampi(R1[a] + e - 1, HHI - 1);
                C2[a][e] = clampi(C1[a] + e - 1, WWI - 1);
            }
        const int hx[3] = {-1, 0, 1}, vx[3] = {1, 2, 1};
        const int hy[3] = {1, 2, 1},  vy[3] = {-1, 0, 1};
        float gxu[3][3], gyu[3][3];
        #pragma unroll
        for (int a = 0; a < 3; ++a)
            #pragma unroll
            for (int b = 0; b < 3; ++b) {
                float sx = 0.f, sy = 0.f;
                #pragma unroll
                for (int e = 0; e < 3; ++e)
                    #pragma unroll
                    for (int f = 0; f < 3; ++f) {
                        const int wx = hx[f] * vx[e], wy = hy[f] * vy[e];
                        if (wx | wy) {
                            float tv = ftim[(size_t)R2[a][e] * WWI + C2[b][f]];
                            if (wx) sx += (float)wx * tv;
                            if (wy) sy += (float)wy * tv;
                        }
                    }
                gxu[a][b] = sx; gyu[a][b] = sy;
            }
        float gxx = 0.f, gxy = 0.f, gyy = 0.f;
        #pragma unroll
        for (int a = 0; a < 3; ++a)
            #pragma unroll
            for (int b = 0; b < 3; ++b) {
                const int w1 = hx[b] * vx[a], w2 = hy[b] * vy[a];
                if (w1) { gxx += (float)w1 * gxu[a][b]; gxy += (float)w1 * gyu[a][b]; }
                if (w2) { gyy += (float)w2 * gyu[a][b]; }
            }
        float sarg = EPS64 - gxy;            // x64 unnormalized throughout
        float num = (sarg > 0.f) ? gyy : ((sarg < 0.f) ? -gyy : 0.f);
        float v = num * frcp(gxx + EPS64);
        bool c2v = (v > T2);
        bool c1v = (v > T1) & !c2v;
        bool c0v = (v >= -T1) & (v <= T1);
        bool c3v = (v < -T2);
        bool have = c2v | c1v | c0v | c3v;
        int r1 = c0v ? y : refli(y - 1, HHI);
        int r2 = c0v ? y : refli(y + 1, HHI);
        int xm = refli(xx - 1, WWI), xp = refli(xx + 1, WWI);
        int co1 = c2v ? xx : (c1v ? xp : xm);
        int co2 = c2v ? xx : (c1v ? xm : xp);
        float ecf = __expf(fpim[(size_t)y * WWI + xx]);
        float d1f = __expf(fpim[(size_t)r1 * WWI + co1]);
        float d2f = __expf(fpim[(size_t)r2 * WWI + co2]);
        float fval = ecf * frcp(d1f + ecf + d2f + EPSF);
        term += (have & valid) ? fval : 0.f;
    }

    // -------- block reduction --------
    for (int off = 32; off; off >>= 1) term += __shfl_down(term, off, 64);
    if (lane == 0) sred[wave] = term;
    __syncthreads();
    if (tid == 0) {
        float b = sred[0] + sred[1] + sred[2] + sred[3];
        if (USE_WS) {
            partial[((size_t)z * gridDim.y + blockIdx.y) * gridDim.x + blockIdx.x] = b;
        } else {
            atomicAdd(partial, b);
        }
    }
}

__global__ __launch_bounds__(1024) void reduce_kernel(
    const float* __restrict__ partial, float* __restrict__ out)
{
    __shared__ float s_red[16];
    float s = 0.f;
    for (int i = threadIdx.x; i < NB; i += 1024) s += partial[i];
    for (int off = 32; off; off >>= 1) s += __shfl_down(s, off, 64);
    if ((threadIdx.x & 63) == 0) s_red[threadIdx.x >> 6] = s;
    __syncthreads();
    if (threadIdx.x == 0) {
        float b = 0.f;
        #pragma unroll
        for (int i = 0; i < 16; ++i) b += s_red[i];
        out[0] = b;
    }
}

extern "C" void kernel_launch(void* const* d_in, const int* in_sizes, int n_in,
                              void* d_out, int out_size, void* d_ws, size_t ws_size,
                              hipStream_t stream) {
    const float* tru = (const float*)d_in[0];
    const float* prd = (const float*)d_in[1];
    float* out = (float*)d_out;
    dim3 grid(GX, GYB, NI);
    dim3 block(256, 1, 1);
    if (ws_size >= (size_t)NB * sizeof(float)) {
        float* ws = (float*)d_ws;
        hipLaunchKernelGGL(nms_main<true>, grid, block, 0, stream, tru, prd, ws);
        hipLaunchKernelGGL(reduce_kernel, dim3(1), dim3(1024), 0, stream, ws, out);
    } else {
        hipMemsetAsync(out, 0, sizeof(float), stream);
        hipLaunchKernelGGL(nms_main<false>, grid, block, 0, stream, tru, prd, out);
    }
}

// Round 8
// 206.364 us; speedup vs baseline: 1.5583x; 1.5583x over previous
//
#include <hip/hip_runtime.h>

#define HHI 1024
#define WWI 1024
#define NI  16
#define HWSZ (HHI * WWI)
#define EPSF  1.1920929e-07f
#define EPS64 7.62939453125e-06f   // 64*EPSF (exact)
#define T1 0.3249196962329063f     // tan(pi/10)
#define T2 1.3763819204711735f     // tan(3pi/10)

#define GX  16                     // interior x-strips (64 cols each)
#define GYB 8                      // y-blocks (128 rows = 4 waves x 32 rows)
#define FRB 4                      // frame-block slots in grid.x (16..19)
#define NB_INT (GX * GYB * NI)     // 2048
#define NB_TOT ((GX + FRB) * GYB * NI)  // 2560
#define NFRAME 8176                // frame pixels per image (2px border)

__device__ __forceinline__ int clampi(int v, int hi) { return v < 0 ? 0 : (v > hi ? hi : v); }
__device__ __forceinline__ int refli(int v, int n)  { return v < 0 ? -v : (v >= n ? 2*n-2-v : v); }
__device__ __forceinline__ float frcp(float x) { return __builtin_amdgcn_rcpf(x); }

// One fully-unrolled pipeline stage; IDX is a literal so (IDX)%5 / (IDX)&3 fold.
// true row -> H ring; pred row -> exp -> LDS ring (wave-private, no barriers);
// output row: classify, then 2 ds_read_b32 of pre-exp'd neighbors.
#define STAGE(IDX, DOPRED, DOOUT) do {                                        \
    {                                                                         \
        const int gy_ = clampi(Y0 - 2 + (IDX), HHI - 1);                      \
        const float* trow_ = timg + (size_t)gy_ * WWI;                        \
        float t0 = trow_[ci0], t1 = trow_[ci1], t2 = trow_[ci2],              \
              t3 = trow_[ci3], t4 = trow_[ci4];                               \
        float s04 = t0 + t4, s13 = t1 + t3;                                   \
        H1[(IDX)%5] = s04 - 2.f * t2;                    /* [1,0,-2,0,1]  */  \
        H2[(IDX)%5] = s04 + 4.f * s13 + 6.f * t2;        /* [1,4,6,4,1]   */  \
        H3[(IDX)%5] = (t4 - t0) + 2.f * (t3 - t1);       /* [-1,-2,0,2,1] */  \
    }                                                                         \
    if (DOPRED) {                                                             \
        const float* prow_ = pimg + (size_t)refli(Y0 + (IDX) - 3, HHI) * WWI; \
        ecP = ecC; ecC = __expf(prow_[ci2]);                                  \
        wring[((IDX)&3)*66 + lane + 1] = ecC;                                 \
        if (lane == 0)  wring[((IDX)&3)*66]      = __expf(prow_[pcL]);        \
        if (lane == 63) wring[((IDX)&3)*66 + 65] = __expf(prow_[pcR]);        \
    }                                                                         \
    if (DOOUT) {                                                              \
        const int y_ = Y0 + (IDX) - 4;                                        \
        const int q0=((IDX)+1)%5, q1=((IDX)+2)%5, q2=((IDX)+3)%5,             \
                  q3=((IDX)+4)%5, q4=(IDX)%5;                                 \
        float gxx = (H1[q0]+H1[q4]) + 4.f*(H1[q1]+H1[q3]) + 6.f*H1[q2];       \
        float gyy = (H2[q0]+H2[q4]) - 2.f*H2[q2];                             \
        float gxy = (H3[q4]-H3[q0]) + 2.f*(H3[q3]-H3[q1]);                    \
        float sarg = EPS64 - gxy;                                             \
        float num = (sarg > 0.f) ? gyy : ((sarg < 0.f) ? -gyy : 0.f);         \
        float v = num * frcp(gxx + EPS64);                                    \
        bool c2v = (v > T2);                                                  \
        bool c1v = (v > T1) & !c2v;                                           \
        bool c0v = (v >= -T1) & (v <= T1);                                    \
        bool c3v = (v < -T2);                                                 \
        bool have = c2v | c1v | c0v | c3v;   /* NaN -> none */                \
        const int sT = (((IDX)+2)&3)*66;   /* (IDX-2)&3 */                    \
        const int sM = (((IDX)+3)&3)*66;   /* (IDX-1)&3 */                    \
        const int sB = ((IDX)&3)*66;                                          \
        int dc1 = c0v ? -1 : (c2v ? 0 : (c1v ? 1 : -1));                      \
        float d1 = wring[(c0v ? sM : sT) + lane + 1 + dc1];                   \
        float d2 = wring[(c0v ? sM : sB) + lane + 1 - dc1];                   \
        float val = ecP * frcp(d1 + ecP + d2 + EPSF);                         \
        bool ok = have & mx & (y_ >= 2) & (y_ <= HHI - 3);                    \
        term += ok ? val : 0.f;                                               \
    }                                                                         \
} while (0)

template <bool USE_WS>
__global__ __launch_bounds__(256, 6) void nms_main(
    const float* __restrict__ tru, const float* __restrict__ prd,
    float* __restrict__ partial)
{
    __shared__ float ring[4][4 * 66];   // [wave][slot*66 + col], 4224 B
    __shared__ float sred[4];
    const int tid  = threadIdx.x;
    const int lane = tid & 63;
    const int wave = tid >> 6;
    const int z = blockIdx.z;
    const float* timg = tru + (size_t)z * HWSZ;
    const float* pimg = prd + (size_t)z * HWSZ;
    float term = 0.f;

    if (blockIdx.x < GX) {
        // -------- interior: per-wave 64x32 strip, 1 col/lane, LDS exp-ring ----
        const int X0 = blockIdx.x * 64;
        const int x  = X0 + lane;
        const int Y0 = blockIdx.y * 128 + wave * 32;
        const bool mx = (x >= 2) & (x <= WWI - 3);
        const int ci0 = clampi(x - 2, WWI - 1);
        const int ci1 = clampi(x - 1, WWI - 1);
        const int ci2 = x;
        const int ci3 = clampi(x + 1, WWI - 1);
        const int ci4 = clampi(x + 2, WWI - 1);
        const int pcL = refli(X0 - 1, WWI);
        const int pcR = refli(X0 + 64, WWI);
        float* wring = &ring[wave][0];

        float H1[5], H2[5], H3[5];
        float ecP = 0.f, ecC = 0.f;

        STAGE(0, 0, 0);  STAGE(1, 0, 0);  STAGE(2, 1, 0);  STAGE(3, 1, 0);
        STAGE(4, 1, 1);  STAGE(5, 1, 1);  STAGE(6, 1, 1);  STAGE(7, 1, 1);
        STAGE(8, 1, 1);  STAGE(9, 1, 1);  STAGE(10, 1, 1); STAGE(11, 1, 1);
        STAGE(12, 1, 1); STAGE(13, 1, 1); STAGE(14, 1, 1); STAGE(15, 1, 1);
        STAGE(16, 1, 1); STAGE(17, 1, 1); STAGE(18, 1, 1); STAGE(19, 1, 1);
        STAGE(20, 1, 1); STAGE(21, 1, 1); STAGE(22, 1, 1); STAGE(23, 1, 1);
        STAGE(24, 1, 1); STAGE(25, 1, 1); STAGE(26, 1, 1); STAGE(27, 1, 1);
        STAGE(28, 1, 1); STAGE(29, 1, 1); STAGE(30, 1, 1); STAGE(31, 1, 1);
        STAGE(32, 1, 1); STAGE(33, 1, 1); STAGE(34, 1, 1); STAGE(35, 1, 1);
    } else {
        // -------- frame: exact nested replicate-pad cascade, 2-px border ------
        const int fid = (blockIdx.x - GX) * GYB + blockIdx.y;   // 0..31
        const int p = fid * 256 + tid;
        const bool valid = p < NFRAME;
        int y, x;
        if (p < 2048)      { y = p >> 10;                   x = p & 1023; }
        else if (p < 4096) { y = 1022 + ((p - 2048) >> 10); x = p & 1023; }
        else { int q = p - 4096; y = 2 + (q >> 2); int xi = q & 3; x = (xi < 2) ? xi : 1020 + xi; }
        if (!valid) { y = 2; x = 0; }

        int R1[3], C1[3], R2[3][3], C2[3][3];
        #pragma unroll
        for (int a = 0; a < 3; ++a) { R1[a] = clampi(y + a - 1, HHI - 1); C1[a] = clampi(x + a - 1, WWI - 1); }
        #pragma unroll
        for (int a = 0; a < 3; ++a)
            #pragma unroll
            for (int e = 0; e < 3; ++e) {
                R2[a][e] = clampi(R1[a] + e - 1, HHI - 1);
                C2[a][e] = clampi(C1[a] + e - 1, WWI - 1);
            }
        const int hx[3] = {-1, 0, 1}, vx[3] = {1, 2, 1};
        const int hy[3] = {1, 2, 1},  vy[3] = {-1, 0, 1};
        float gxu[3][3], gyu[3][3];
        #pragma unroll
        for (int a = 0; a < 3; ++a)
            #pragma unroll
            for (int b = 0; b < 3; ++b) {
                float sx = 0.f, sy = 0.f;
                #pragma unroll
                for (int e = 0; e < 3; ++e)
                    #pragma unroll
                    for (int f = 0; f < 3; ++f) {
                        const int wx = hx[f] * vx[e], wy = hy[f] * vy[e];
                        if (wx | wy) {
                            float tv = timg[(size_t)R2[a][e] * WWI + C2[b][f]];
                            if (wx) sx += (float)wx * tv;
                            if (wy) sy += (float)wy * tv;
                        }
                    }
                gxu[a][b] = sx; gyu[a][b] = sy;
            }
        float gxx = 0.f, gxy = 0.f, gyy = 0.f;
        #pragma unroll
        for (int a = 0; a < 3; ++a)
            #pragma unroll
            for (int b = 0; b < 3; ++b) {
                const int w1 = hx[b] * vx[a], w2 = hy[b] * vy[a];
                if (w1) { gxx += (float)w1 * gxu[a][b]; gxy += (float)w1 * gyu[a][b]; }
                if (w2) { gyy += (float)w2 * gyu[a][b]; }
            }
        float sarg = EPS64 - gxy;            // x64 unnormalized throughout
        float num = (sarg > 0.f) ? gyy : ((sarg < 0.f) ? -gyy : 0.f);
        float v = num * frcp(gxx + EPS64);
        bool c2v = (v > T2);
        bool c1v = (v > T1) & !c2v;
        bool c0v = (v >= -T1) & (v <= T1);
        bool c3v = (v < -T2);
        bool have = c2v | c1v | c0v | c3v;
        int r1 = c0v ? y : refli(y - 1, HHI);
        int r2 = c0v ? y : refli(y + 1, HHI);
        int xm = refli(x - 1, WWI), xp = refli(x + 1, WWI);
        int co1 = c2v ? x : (c1v ? xp : xm);
        int co2 = c2v ? x : (c1v ? xm : xp);
        float ecf = __expf(pimg[(size_t)y * WWI + x]);
        float d1f = __expf(pimg[(size_t)r1 * WWI + co1]);
        float d2f = __expf(pimg[(size_t)r2 * WWI + co2]);
        float fval = ecf * frcp(d1f + ecf + d2f + EPSF);
        term += (have & valid) ? fval : 0.f;
    }

    // -------- block reduction --------
    for (int off = 32; off; off >>= 1) term += __shfl_down(term, off, 64);
    if (lane == 0) sred[wave] = term;
    __syncthreads();
    if (tid == 0) {
        float b = sred[0] + sred[1] + sred[2] + sred[3];
        if (USE_WS) {
            const int slot = (blockIdx.x < GX)
                ? ((z * GYB + blockIdx.y) * GX + blockIdx.x)
                : (NB_INT + z * 32 + ((blockIdx.x - GX) * GYB + blockIdx.y));
            partial[slot] = b;
        } else {
            atomicAdd(partial, b);
        }
    }
}

__global__ __launch_bounds__(1024) void reduce_kernel(
    const float* __restrict__ partial, float* __restrict__ out)
{
    __shared__ float s_red[16];
    float s = 0.f;
    for (int i = threadIdx.x; i < NB_TOT; i += 1024) s += partial[i];
    for (int off = 32; off; off >>= 1) s += __shfl_down(s, off, 64);
    if ((threadIdx.x & 63) == 0) s_red[threadIdx.x >> 6] = s;
    __syncthreads();
    if (threadIdx.x == 0) {
        float b = 0.f;
        #pragma unroll
        for (int i = 0; i < 16; ++i) b += s_red[i];
        out[0] = b;
    }
}

extern "C" void kernel_launch(void* const* d_in, const int* in_sizes, int n_in,
                              void* d_out, int out_size, void* d_ws, size_t ws_size,
                              hipStream_t stream) {
    const float* tru = (const float*)d_in[0];
    const float* prd = (const float*)d_in[1];
    float* out = (float*)d_out;
    dim3 grid(GX + FRB, GYB, NI);
    dim3 block(256, 1, 1);
    if (ws_size >= (size_t)NB_TOT * sizeof(float)) {
        float* ws = (float*)d_ws;
        hipLaunchKernelGGL(nms_main<true>, grid, block, 0, stream, tru, prd, ws);
        hipLaunchKernelGGL(reduce_kernel, dim3(1), dim3(1024), 0, stream, ws, out);
    } else {
        hipMemsetAsync(out, 0, sizeof(float), stream);
        hipLaunchKernelGGL(nms_main<false>, grid, block, 0, stream, tru, prd, out);
    }
}

// Round 9
// 74.037 us; speedup vs baseline: 4.3435x; 2.7873x over previous
//
#include <hip/hip_runtime.h>

#define HHI 1024
#define WWI 1024
#define NI  16
#define HWSZ (HHI * WWI)
#define EPSF  1.1920929e-07f
#define EPS64 7.62939453125e-06f   // 64*EPSF (exact)
#define T1 0.3249196962329063f     // tan(pi/10)
#define T2 1.3763819204711735f     // tan(3pi/10)

#define GX  16                     // interior x-strips (64 cols each)
#define GYB 8                      // y-blocks (128 rows = 4 waves x 32 rows)
#define FRB 4                      // frame-block slots in grid.x (16..19)
#define NB_INT (GX * GYB * NI)     // 2048
#define NB_TOT ((GX + FRB) * GYB * NI)  // 2560
#define NFRAME 8176                // frame pixels per image (2px border)

__device__ __forceinline__ int clampi(int v, int hi) { return v < 0 ? 0 : (v > hi ? hi : v); }
__device__ __forceinline__ int refli(int v, int n)  { return v < 0 ? -v : (v >= n ? 2*n-2-v : v); }
__device__ __forceinline__ float frcp(float x) { return __builtin_amdgcn_rcpf(x); }

template <bool USE_WS>
__global__ __launch_bounds__(256, 8) void nms_main(
    const float* __restrict__ tru, const float* __restrict__ prd,
    float* __restrict__ partial)
{
    __shared__ float sred[4];
    const int tid  = threadIdx.x;
    const int lane = tid & 63;
    const int wave = tid >> 6;
    const int z = blockIdx.z;
    const float* timg = tru + (size_t)z * HWSZ;
    const float* pimg = prd + (size_t)z * HWSZ;
    float term = 0.f;

    if (blockIdx.x < GX) {
        // -------- interior: per-wave 64x32 strip, 1 col/lane, reg rings --------
        const int x  = blockIdx.x * 64 + lane;
        const int Y0 = blockIdx.y * 128 + wave * 32;
        const int ci0 = clampi(x - 2, WWI - 1);
        const int ci1 = clampi(x - 1, WWI - 1);
        const int ci2 = x;
        const int ci3 = clampi(x + 1, WWI - 1);
        const int ci4 = clampi(x + 2, WWI - 1);
        const int cxm = refli(x - 1, WWI);   // pred col x-1 (reflect)
        const int cxp = refli(x + 1, WWI);   // pred col x+1 (reflect)
        const bool mx = (x >= 2) & (x <= WWI - 3);

        float H1[5], H2[5], H3[5];
        // pred exp ring: rows T=y-1, M=y, B=y+1; cols m=x-1, c=x, p=x+1
        float PmT = 0.f, PcT = 0.f, PpT = 0.f;
        float PmM = 0.f, PcM = 0.f, PpM = 0.f;
        float PmB = 0.f, PcB = 0.f, PpB = 0.f;

        #pragma unroll 1
        for (int ch = 0; ch < 8; ++ch) {
            #pragma unroll
            for (int pos = 0; pos < 5; ++pos) {
                const int i = ch * 5 + pos;      // stage 0..39 (36..39 skipped)
                if (i < 36) {
                    // true row -> horizontal composites (x64 unnormalized)
                    const int s  = Y0 - 2 + i;
                    const int gy = clampi(s, HHI - 1);
                    const float* trow = timg + (size_t)gy * WWI;
                    float t0 = trow[ci0], t1 = trow[ci1], t2 = trow[ci2],
                          t3 = trow[ci3], t4 = trow[ci4];
                    float s04 = t0 + t4, s13 = t1 + t3;
                    H1[pos] = s04 - 2.f * t2;                 // [1,0,-2,0,1]  (gxx h)
                    H2[pos] = s04 + 4.f * s13 + 6.f * t2;     // [1,4,6,4,1]   (gyy h)
                    H3[pos] = (t4 - t0) + 2.f * (t3 - t1);    // [-1,-2,0,2,1] (gxy h)

                    // pred row (fixed addresses) -> exp -> shift ring
                    if (i >= 2) {
                        PmT = PmM; PcT = PcM; PpT = PpM;
                        PmM = PmB; PcM = PcB; PpM = PpB;
                        const float* prow = pimg + (size_t)refli(Y0 + i - 3, HHI) * WWI;
                        PmB = __expf(prow[cxm]);
                        PcB = __expf(prow[ci2]);
                        PpB = __expf(prow[cxp]);
                    }

                    // output row y = Y0 + i - 4
                    if (i >= 4) {
                        const int y = s - 2;
                        const int q0 = (pos + 1) % 5, q1 = (pos + 2) % 5,
                                  q2 = (pos + 3) % 5, q3 = (pos + 4) % 5, q4 = pos;
                        float gxx = (H1[q0] + H1[q4]) + 4.f * (H1[q1] + H1[q3]) + 6.f * H1[q2];
                        float gyy = (H2[q0] + H2[q4]) - 2.f * H2[q2];
                        float gxy = (H3[q4] - H3[q0]) + 2.f * (H3[q3] - H3[q1]);
                        float sarg = EPS64 - gxy;
                        float num = (sarg > 0.f) ? gyy : ((sarg < 0.f) ? -gyy : 0.f);
                        float v = num * frcp(gxx + EPS64);
                        bool c2v = (v > T2);
                        bool c1v = (v > T1) & !c2v;
                        bool c0v = (v >= -T1) & (v <= T1);
                        bool c3v = (v < -T2);
                        bool have = c2v | c1v | c0v | c3v;   // NaN -> none
                        // neighbor selects from ring (verified vs gather table):
                        //  c0 (horiz): E[y][x-1], E[y][x+1]
                        //  c2 (vert) : E[y-1][x], E[y+1][x]
                        //  c1 (anti) : E[y-1][x+1], E[y+1][x-1]
                        //  c3 (diag) : E[y-1][x-1], E[y+1][x+1]
                        float d1 = c0v ? PmM : (c2v ? PcT : (c1v ? PpT : PmT));
                        float d2 = c0v ? PpM : (c2v ? PcB : (c1v ? PmB : PpB));
                        float ec = PcM;
                        float val = ec * frcp(d1 + ec + d2 + EPSF);
                        bool ok = have & mx & (y >= 2) & (y <= HHI - 3);
                        term += ok ? val : 0.f;
                    }
                }
            }
        }
    } else {
        // -------- frame: exact nested replicate-pad cascade, 2-px border ------
        const int fid = (blockIdx.x - GX) * GYB + blockIdx.y;   // 0..31
        const int p = fid * 256 + tid;
        const bool valid = p < NFRAME;
        int y, x;
        if (p < 2048)      { y = p >> 10;                   x = p & 1023; }
        else if (p < 4096) { y = 1022 + ((p - 2048) >> 10); x = p & 1023; }
        else { int q = p - 4096; y = 2 + (q >> 2); int xi = q & 3; x = (xi < 2) ? xi : 1020 + xi; }
        if (!valid) { y = 2; x = 0; }

        int R1[3], C1[3], R2[3][3], C2[3][3];
        #pragma unroll
        for (int a = 0; a < 3; ++a) { R1[a] = clampi(y + a - 1, HHI - 1); C1[a] = clampi(x + a - 1, WWI - 1); }
        #pragma unroll
        for (int a = 0; a < 3; ++a)
            #pragma unroll
            for (int e = 0; e < 3; ++e) {
                R2[a][e] = clampi(R1[a] + e - 1, HHI - 1);
                C2[a][e] = clampi(C1[a] + e - 1, WWI - 1);
            }
        const int hx[3] = {-1, 0, 1}, vx[3] = {1, 2, 1};
        const int hy[3] = {1, 2, 1},  vy[3] = {-1, 0, 1};
        float gxu[3][3], gyu[3][3];
        #pragma unroll
        for (int a = 0; a < 3; ++a)
            #pragma unroll
            for (int b = 0; b < 3; ++b) {
                float sx = 0.f, sy = 0.f;
                #pragma unroll
                for (int e = 0; e < 3; ++e)
                    #pragma unroll
                    for (int f = 0; f < 3; ++f) {
                        const int wx = hx[f] * vx[e], wy = hy[f] * vy[e];
                        if (wx | wy) {
                            float tv = timg[(size_t)R2[a][e] * WWI + C2[b][f]];
                            if (wx) sx += (float)wx * tv;
                            if (wy) sy += (float)wy * tv;
                        }
                    }
                gxu[a][b] = sx; gyu[a][b] = sy;
            }
        float gxx = 0.f, gxy = 0.f, gyy = 0.f;
        #pragma unroll
        for (int a = 0; a < 3; ++a)
            #pragma unroll
            for (int b = 0; b < 3; ++b) {
                const int w1 = hx[b] * vx[a], w2 = hy[b] * vy[a];
                if (w1) { gxx += (float)w1 * gxu[a][b]; gxy += (float)w1 * gyu[a][b]; }
                if (w2) { gyy += (float)w2 * gyu[a][b]; }
            }
        float sarg = EPS64 - gxy;            // x64 unnormalized throughout
        float num = (sarg > 0.f) ? gyy : ((sarg < 0.f) ? -gyy : 0.f);
        float v = num * frcp(gxx + EPS64);
        bool c2v = (v > T2);
        bool c1v = (v > T1) & !c2v;
        bool c0v = (v >= -T1) & (v <= T1);
        bool c3v = (v < -T2);
        bool have = c2v | c1v | c0v | c3v;
        int r1 = c0v ? y : refli(y - 1, HHI);
        int r2 = c0v ? y : refli(y + 1, HHI);
        int xm = refli(x - 1, WWI), xp = refli(x + 1, WWI);
        int co1 = c2v ? x : (c1v ? xp : xm);
        int co2 = c2v ? x : (c1v ? xm : xp);
        float ecf = __expf(pimg[(size_t)y * WWI + x]);
        float d1f = __expf(pimg[(size_t)r1 * WWI + co1]);
        float d2f = __expf(pimg[(size_t)r2 * WWI + co2]);
        float fval = ecf * frcp(d1f + ecf + d2f + EPSF);
        term += (have & valid) ? fval : 0.f;
    }

    // -------- block reduction --------
    for (int off = 32; off; off >>= 1) term += __shfl_down(term, off, 64);
    if (lane == 0) sred[wave] = term;
    __syncthreads();
    if (tid == 0) {
        float b = sred[0] + sred[1] + sred[2] + sred[3];
        if (USE_WS) {
            const int slot = (blockIdx.x < GX)
                ? ((z * GYB + blockIdx.y) * GX + blockIdx.x)
                : (NB_INT + z * 32 + ((blockIdx.x - GX) * GYB + blockIdx.y));
            partial[slot] = b;
        } else {
            atomicAdd(partial, b);
        }
    }
}

__global__ __launch_bounds__(1024) void reduce_kernel(
    const float* __restrict__ partial, float* __restrict__ out)
{
    __shared__ float s_red[16];
    float s = 0.f;
    for (int i = threadIdx.x; i < NB_TOT; i += 1024) s += partial[i];
    for (int off = 32; off; off >>= 1) s += __shfl_down(s, off, 64);
    if ((threadIdx.x & 63) == 0) s_red[threadIdx.x >> 6] = s;
    __syncthreads();
    if (threadIdx.x == 0) {
        float b = 0.f;
        #pragma unroll
        for (int i = 0; i < 16; ++i) b += s_red[i];
        out[0] = b;
    }
}

extern "C" void kernel_launch(void* const* d_in, const int* in_sizes, int n_in,
                              void* d_out, int out_size, void* d_ws, size_t ws_size,
                              hipStream_t stream) {
    const float* tru = (const float*)d_in[0];
    const float* prd = (const float*)d_in[1];
    float* out = (float*)d_out;
    dim3 grid(GX + FRB, GYB, NI);
    dim3 block(256, 1, 1);
    if (ws_size >= (size_t)NB_TOT * sizeof(float)) {
        float* ws = (float*)d_ws;
        hipLaunchKernelGGL(nms_main<true>, grid, block, 0, stream, tru, prd, ws);
        hipLaunchKernelGGL(reduce_kernel, dim3(1), dim3(1024), 0, stream, ws, out);
    } else {
        hipMemsetAsync(out, 0, sizeof(float), stream);
        hipLaunchKernelGGL(nms_main<false>, grid, block, 0, stream, tru, prd, out);
    }
}